// Round 20
// baseline (474.969 us; speedup 1.0000x reference)
//
#include <hip/hip_runtime.h>
#include <math.h>

#define N_ 16
#define C_ 256
#define H_ 128
#define W_ 128
#define TC_ 8
#define S_ 257   // H + W + 1
#define EPS_ 1e-5f
#define NBLK 4096   // one plane per block

// ws layout (floats):
//   xcat : [N*C][S][2] = 2105344
//   ahg  : [N*C][H]    = 524288   (pure sigmoid; a_c folded in phase 3)
//   awg  : [N*C][W]    = 524288
//   y256g: [N][16]     = 256
//   cnt  : per-n, 64 uints (barrier1 +0 target 256; barrier2 +32 target 32)
#define XCT_OFF  0
#define AH_OFF   2105344
#define AW_OFF   (AH_OFF + 524288)
#define Y256_OFF (AW_OFF + 524288)
#define CNT_OFF  (Y256_OFF + 256)

typedef float f4n __attribute__((ext_vector_type(4)));

// ---- DPP helpers (VALU pipe) ------------------------------------------------
template <int CTRL>
__device__ __forceinline__ float dpp_zf(float x) {
    return __int_as_float(__builtin_amdgcn_update_dpp(
        0, __float_as_int(x), CTRL, 0xF, 0xF, true));
}
template <int CTRL>
__device__ __forceinline__ float dpp_keep(float x) {
    return __int_as_float(__builtin_amdgcn_update_dpp(
        __float_as_int(x), __float_as_int(x), CTRL, 0xF, 0xF, false));
}
#define SHR1 0x111
#define SHR2 0x112
#define SHR4 0x114
#define SHR8 0x118
#define BC15 0x142

// lane 31 holds sum/max of lanes 0..31; lane 63 of lanes 32..63
__device__ __forceinline__ float rowsum32(float x) {
    x += dpp_zf<SHR1>(x);
    x += dpp_zf<SHR2>(x);
    x += dpp_zf<SHR4>(x);
    x += dpp_zf<SHR8>(x);
    x += dpp_zf<BC15>(x);
    return x;
}
__device__ __forceinline__ float rowmax32(float x) {
    x = fmaxf(x, dpp_keep<SHR1>(x));
    x = fmaxf(x, dpp_keep<SHR2>(x));
    x = fmaxf(x, dpp_keep<SHR4>(x));
    x = fmaxf(x, dpp_keep<SHR8>(x));
    x = fmaxf(x, dpp_keep<BC15>(x));
    return x;
}

__global__ __launch_bounds__(256, 3) void mega(
    const float* __restrict__ x,
    const float* __restrict__ w1, const float* __restrict__ b1,
    const float* __restrict__ gam, const float* __restrict__ bet,
    const float* __restrict__ mu, const float* __restrict__ var,
    const float* __restrict__ w2, const float* __restrict__ b2,
    const float* __restrict__ w3, const float* __restrict__ b3,
    const float* __restrict__ w4, const float* __restrict__ b4,
    float* __restrict__ xcat, float* __restrict__ ahg, float* __restrict__ awg,
    float* __restrict__ y256g, unsigned* __restrict__ cnt,
    float* __restrict__ out)
{
    const int b = blockIdx.x;
    const int n = b >> 8, c = b & 255;          // plane = b = n*256 + c
    const int tid = threadIdx.x, lane = tid & 63, wv = tid >> 6;
    __shared__ __align__(16) float smf[6448];   // 25.8 KB, phase-overlaid

    const f4n* x4 = reinterpret_cast<const f4n*>(x) + (size_t)b * 4096;
    float2* xcat2 = reinterpret_cast<float2*>(xcat) + (size_t)b * S_;

    // ---------------- phase 1: plane -> registers + stats -------------------
    // thread covers cols 4*(tid&31)+{0..3}; iteration it: row it*8 + (tid>>5)
    f4n xr[16];
    float4 cs = make_float4(0.f, 0.f, 0.f, 0.f);
    float4 cm = make_float4(-INFINITY, -INFINITY, -INFINITY, -INFINITY);

    #pragma unroll
    for (int it = 0; it < 16; ++it) {
        xr[it] = x4[it * 256 + tid];
        const f4n v = xr[it];
        cs.x += v.x; cs.y += v.y; cs.z += v.z; cs.w += v.w;
        cm.x = fmaxf(cm.x, v.x); cm.y = fmaxf(cm.y, v.y);
        cm.z = fmaxf(cm.z, v.z); cm.w = fmaxf(cm.w, v.w);

        float rs = (v.x + v.y) + (v.z + v.w);
        float rm = fmaxf(fmaxf(v.x, v.y), fmaxf(v.z, v.w));
        rs = rowsum32(rs);
        rm = rowmax32(rm);
        if ((lane & 31) == 31)
            xcat2[it * 8 + wv * 2 + (lane >> 5)] =
                make_float2(rs * (1.f / 128.f), rm);
    }

    // columns: combine the wave's two row-groups, then cross-wave via LDS
    cs.x += __shfl_xor(cs.x, 32); cs.y += __shfl_xor(cs.y, 32);
    cs.z += __shfl_xor(cs.z, 32); cs.w += __shfl_xor(cs.w, 32);
    cm.x = fmaxf(cm.x, __shfl_xor(cm.x, 32));
    cm.y = fmaxf(cm.y, __shfl_xor(cm.y, 32));
    cm.z = fmaxf(cm.z, __shfl_xor(cm.z, 32));
    cm.w = fmaxf(cm.w, __shfl_xor(cm.w, 32));

    {
        float4* scr_s = reinterpret_cast<float4*>(smf);         // [4][32]
        float4* scr_m = reinterpret_cast<float4*>(smf) + 128;   // [4][32]
        if (lane < 32) {
            scr_s[wv * 32 + lane] = make_float4(cs.x, cs.y, cs.z, cs.w);
            scr_m[wv * 32 + lane] = make_float4(cm.x, cm.y, cm.z, cm.w);
        }
        __syncthreads();

        if (tid < 32) {
            const float4 s0 = scr_s[tid],      s1 = scr_s[32 + tid],
                         s2 = scr_s[64 + tid], s3 = scr_s[96 + tid];
            const float4 m0 = scr_m[tid],      m1 = scr_m[32 + tid],
                         m2 = scr_m[64 + tid], m3 = scr_m[96 + tid];
            float4 S, M;
            S.x = (s0.x + s1.x) + (s2.x + s3.x);
            S.y = (s0.y + s1.y) + (s2.y + s3.y);
            S.z = (s0.z + s1.z) + (s2.z + s3.z);
            S.w = (s0.w + s1.w) + (s2.w + s3.w);
            M.x = fmaxf(fmaxf(m0.x, m1.x), fmaxf(m2.x, m3.x));
            M.y = fmaxf(fmaxf(m0.y, m1.y), fmaxf(m2.y, m3.y));
            M.z = fmaxf(fmaxf(m0.z, m1.z), fmaxf(m2.z, m3.z));
            M.w = fmaxf(fmaxf(m0.w, m1.w), fmaxf(m2.w, m3.w));

            const int w0 = 4 * tid;
            xcat2[128 + w0 + 0] = make_float2(S.x * (1.f / 128.f), M.x);
            xcat2[128 + w0 + 1] = make_float2(S.y * (1.f / 128.f), M.y);
            xcat2[128 + w0 + 2] = make_float2(S.z * (1.f / 128.f), M.z);
            xcat2[128 + w0 + 3] = make_float2(S.w * (1.f / 128.f), M.w);

            float gs = (S.x + S.y) + (S.z + S.w);
            float gm = fmaxf(fmaxf(M.x, M.y), fmaxf(M.z, M.w));
            #pragma unroll
            for (int m = 16; m >= 1; m >>= 1) {
                gs += __shfl_xor(gs, m);
                gm = fmaxf(gm, __shfl_xor(gm, m));
            }
            if (tid == 0) xcat2[256] = make_float2(gs * (1.f / 16384.f), gm);
        }
        __syncthreads();   // scr dead; smf reusable
    }

    // ------------- barrier 1: all 256 blocks of my n wrote xcat -------------
    if (tid == 0) {
        unsigned* c1 = cnt + n * 64;
        __hip_atomic_fetch_add(c1, 1u, __ATOMIC_RELEASE, __HIP_MEMORY_SCOPE_AGENT);
        while (__hip_atomic_load(c1, __ATOMIC_RELAXED, __HIP_MEMORY_SCOPE_AGENT) < 256u)
            __builtin_amdgcn_s_sleep(16);
        (void)__hip_atomic_load(c1, __ATOMIC_ACQUIRE, __HIP_MEMORY_SCOPE_AGENT);
    }
    __syncthreads();

    // ---------------- phase 2a (blocks c<32): distributed attention rows ----
    if (c < 32) {
        float* w1s = smf;
        float* red = smf + 2048;
        float* ys  = smf + 6272;
        const float2* xc2 = reinterpret_cast<const float2*>(xcat) + (size_t)n * C_ * S_;
        const int s0 = c * 8;

        for (int i = tid; i < TC_ * C_; i += 256) w1s[i] = w1[i];
        __syncthreads();

        {   // stage A: partial einsum
            const int cgrp = tid >> 3, si = tid & 7;
            const int s = s0 + si;
            float acc[16];
            #pragma unroll
            for (int j = 0; j < 16; ++j) acc[j] = 0.f;
            #pragma unroll
            for (int i = 0; i < 8; ++i) {
                const int cc = cgrp * 8 + i;
                const float2 v = xc2[cc * S_ + s];
                #pragma unroll
                for (int t = 0; t < TC_; ++t) {
                    const float w = w1s[t * C_ + cc];
                    acc[t * 2 + 0] += v.x * w;
                    acc[t * 2 + 1] += v.y * w;
                }
            }
            #pragma unroll
            for (int j = 0; j < 16; ++j) red[(si * 16 + j) * 33 + cgrp] = acc[j];
        }
        __syncthreads();

        if (tid < 128) {   // stage B: reduce + BN + hswish
            const int si2 = tid >> 4, j = tid & 15, t = j >> 1;
            float z = 0.f;
            #pragma unroll
            for (int g = 0; g < 32; ++g) z += red[(si2 * 16 + j) * 33 + g];
            const float inv = gam[t] * rsqrtf(var[t] + EPS_);
            float y = (z + b1[t] - mu[t]) * inv + bet[t];
            y = y * fminf(fmaxf(y + 3.f, 0.f), 6.f) * (1.f / 6.f);
            ys[si2 * 17 + j] = y;
        }
        __syncthreads();

        if (c == 31) {   // tail s = 256 -> y256g (block-uniform)
            const int cc = tid;
            const float2 v = xc2[cc * S_ + 256];
            float pj[16];
            #pragma unroll
            for (int t = 0; t < TC_; ++t) {
                const float w = w1s[t * C_ + cc];
                pj[t * 2 + 0] = v.x * w;
                pj[t * 2 + 1] = v.y * w;
            }
            __syncthreads();               // done with w1s/red
            float* red2 = smf;             // [256][17]
            float* redB = smf + 4400;      // [16][17]
            #pragma unroll
            for (int j = 0; j < 16; ++j) red2[tid * 17 + j] = pj[j];
            __syncthreads();
            {
                const int g = tid >> 4, j = tid & 15;
                float z = 0.f;
                #pragma unroll
                for (int m = 0; m < 16; ++m) z += red2[(g * 16 + m) * 17 + j];
                redB[j * 17 + g] = z;
            }
            __syncthreads();
            if (tid < 16) {
                const int j = tid, t = j >> 1;
                float z = 0.f;
                #pragma unroll
                for (int g = 0; g < 16; ++g) z += redB[j * 17 + g];
                const float inv = gam[t] * rsqrtf(var[t] + EPS_);
                float y = (z + b1[t] - mu[t]) * inv + bet[t];
                y = y * fminf(fmaxf(y + 3.f, 0.f), 6.f) * (1.f / 6.f);
                y256g[n * 16 + j] = y;
            }
            __syncthreads();
        }

        {   // stage C: attention row for ALL 256 channels at my 8 s-positions
            const int o = tid;
            const bool is_h = (c < 16);
            const float* wX = is_h ? w2 : w3;
            const float zb = is_h ? b2[o] : b3[o];
            float4 wr[4];
            const float4* wvp = reinterpret_cast<const float4*>(wX + o * 16);
            #pragma unroll
            for (int q = 0; q < 4; ++q) wr[q] = wvp[q];

            float r[8];
            #pragma unroll
            for (int si = 0; si < 8; ++si) {
                float z = zb;
                #pragma unroll
                for (int q = 0; q < 4; ++q) {
                    z += ys[si * 17 + q * 4 + 0] * wr[q].x
                       + ys[si * 17 + q * 4 + 1] * wr[q].y
                       + ys[si * 17 + q * 4 + 2] * wr[q].z
                       + ys[si * 17 + q * 4 + 3] * wr[q].w;
                }
                r[si] = 1.f / (1.f + expf(-z));
            }
            float* og = is_h ? (ahg + (size_t)(n * C_ + o) * H_ + s0)
                             : (awg + (size_t)(n * C_ + o) * W_ + (s0 - 128));
            *reinterpret_cast<float4*>(og)     = make_float4(r[0], r[1], r[2], r[3]);
            *reinterpret_cast<float4*>(og + 4) = make_float4(r[4], r[5], r[6], r[7]);
        }
        __syncthreads();
        if (tid == 0)
            __hip_atomic_fetch_add(cnt + n * 64 + 32, 1u,
                                   __ATOMIC_RELEASE, __HIP_MEMORY_SCOPE_AGENT);
    }

    // ------------- barrier 2: attention rows of my n complete ---------------
    if (tid == 0) {
        unsigned* c2 = cnt + n * 64 + 32;
        while (__hip_atomic_load(c2, __ATOMIC_RELAXED, __HIP_MEMORY_SCOPE_AGENT) < 32u)
            __builtin_amdgcn_s_sleep(16);
        (void)__hip_atomic_load(c2, __ATOMIC_ACQUIRE, __HIP_MEMORY_SCOPE_AGENT);
    }
    __syncthreads();

    // ---------------- phase 3: out = xr * a_h * a_w * a_c (nt stores) -------
    {
        float z = b4[c];
        const float4* w4v = reinterpret_cast<const float4*>(w4 + c * 16);
        const float4* yv  = reinterpret_cast<const float4*>(y256g + n * 16);
        #pragma unroll
        for (int q = 0; q < 4; ++q) {
            const float4 ww = w4v[q], yy = yv[q];
            z += yy.x * ww.x + yy.y * ww.y + yy.z * ww.z + yy.w * ww.w;
        }
        const float ac = 1.f / (1.f + expf(-z));

        const float4 aw =
            reinterpret_cast<const float4*>(awg + (size_t)b * W_)[tid & 31];
        const float* ah = ahg + (size_t)b * H_;
        f4n* o4 = reinterpret_cast<f4n*>(out) + (size_t)b * 4096;

        #pragma unroll
        for (int it = 0; it < 16; ++it) {
            const float s = ac * ah[it * 8 + (tid >> 5)];   // L1 broadcast
            f4n v = xr[it];
            v.x *= s * aw.x; v.y *= s * aw.y; v.z *= s * aw.z; v.w *= s * aw.w;
            __builtin_nontemporal_store(v, &o4[it * 256 + tid]);
        }
    }
}

extern "C" void kernel_launch(void* const* d_in, const int* in_sizes, int n_in,
                              void* d_out, int out_size, void* d_ws, size_t ws_size,
                              hipStream_t stream) {
    const float* x   = (const float*)d_in[0];
    const float* w1  = (const float*)d_in[1];
    const float* b1  = (const float*)d_in[2];
    const float* gam = (const float*)d_in[3];
    const float* bet = (const float*)d_in[4];
    const float* mu  = (const float*)d_in[5];
    const float* var = (const float*)d_in[6];
    const float* w2  = (const float*)d_in[7];
    const float* b2  = (const float*)d_in[8];
    const float* w3  = (const float*)d_in[9];
    const float* b3  = (const float*)d_in[10];
    const float* w4  = (const float*)d_in[11];
    const float* b4  = (const float*)d_in[12];

    float* ws    = (float*)d_ws;
    float* xcat  = ws + XCT_OFF;
    float* ahg   = ws + AH_OFF;
    float* awg   = ws + AW_OFF;
    float* y256g = ws + Y256_OFF;
    unsigned* cnt = (unsigned*)(ws + CNT_OFF);
    float* out   = (float*)d_out;

    hipMemsetAsync((void*)cnt, 0, 16 * 64 * sizeof(unsigned), stream);
    mega<<<NBLK, 256, 0, stream>>>(x, w1, b1, gam, bet, mu, var,
                                   w2, b2, w3, b3, w4, b4,
                                   xcat, ahg, awg, y256g, cnt, out);
}

// Round 21
// 149.761 us; speedup vs baseline: 3.1715x; 3.1715x over previous
//
#include <hip/hip_runtime.h>
#include <math.h>

#define N_ 16
#define C_ 256
#define H_ 128
#define W_ 128
#define TC_ 8
#define S_ 257   // H + W + 1
#define EPS_ 1e-5f
#define NBLK 512
#define BPN 32   // blocks per n (k2)

// ws layout (floats):
//   xcat : [N*C][S][2] = 2105344
//   ahg  : [N*C][H]    = 524288   (pure sigmoid; a_c folded in k3)
//   awg  : [N*C][W]    = 524288
//   y256g: [N][16]     = 256
#define XCT_OFF  0
#define AH_OFF   2105344
#define AW_OFF   (AH_OFF + 524288)
#define Y256_OFF (AW_OFF + 524288)

typedef float f4n __attribute__((ext_vector_type(4)));

// ---- DPP helpers (VALU pipe — no LDS/DS traffic) ---------------------------
template <int CTRL>
__device__ __forceinline__ float dpp_zf(float x) {   // invalid lanes -> 0
    return __int_as_float(__builtin_amdgcn_update_dpp(
        0, __float_as_int(x), CTRL, 0xF, 0xF, true));
}
template <int CTRL>
__device__ __forceinline__ float dpp_keep(float x) { // invalid lanes -> x
    return __int_as_float(__builtin_amdgcn_update_dpp(
        __float_as_int(x), __float_as_int(x), CTRL, 0xF, 0xF, false));
}
#define SHR1 0x111
#define SHR2 0x112
#define SHR4 0x114
#define SHR8 0x118
#define BC15 0x142

__device__ __forceinline__ float rowsum32(float x) {
    x += dpp_zf<SHR1>(x);
    x += dpp_zf<SHR2>(x);
    x += dpp_zf<SHR4>(x);
    x += dpp_zf<SHR8>(x);
    x += dpp_zf<BC15>(x);
    return x;
}
__device__ __forceinline__ float rowmax32(float x) {
    x = fmaxf(x, dpp_keep<SHR1>(x));
    x = fmaxf(x, dpp_keep<SHR2>(x));
    x = fmaxf(x, dpp_keep<SHR4>(x));
    x = fmaxf(x, dpp_keep<SHR8>(x));
    x = fmaxf(x, dpp_keep<BC15>(x));
    return x;
}

// ---------------- k1: wave-private stats (at measured read ceiling) ---------
__global__ __launch_bounds__(256, 4) void k1_stats(
    const float* __restrict__ x, float* __restrict__ xcat)
{
    const int tid = threadIdx.x, lane = tid & 63, wv = tid >> 6;
    const int p = blockIdx.x * 4 + wv;              // one plane per wave
    const float4* xt = reinterpret_cast<const float4*>(x) + (size_t)p * 4096;
    float2* xcat2 = reinterpret_cast<float2*>(xcat) + (size_t)p * S_;

    float4 cs = make_float4(0.f, 0.f, 0.f, 0.f);
    float4 cm = make_float4(-INFINITY, -INFINITY, -INFINITY, -INFINITY);

    #pragma unroll 8
    for (int it = 0; it < 64; ++it) {
        const float4 v = xt[it * 64 + lane];
        cs.x += v.x; cs.y += v.y; cs.z += v.z; cs.w += v.w;
        cm.x = fmaxf(cm.x, v.x); cm.y = fmaxf(cm.y, v.y);
        cm.z = fmaxf(cm.z, v.z); cm.w = fmaxf(cm.w, v.w);

        float rs = (v.x + v.y) + (v.z + v.w);
        float rm = fmaxf(fmaxf(v.x, v.y), fmaxf(v.z, v.w));
        rs = rowsum32(rs);
        rm = rowmax32(rm);
        if ((lane & 31) == 31)
            xcat2[it * 2 + (lane >> 5)] = make_float2(rs * (1.f / 128.f), rm);
    }

    cs.x += __shfl_xor(cs.x, 32); cs.y += __shfl_xor(cs.y, 32);
    cs.z += __shfl_xor(cs.z, 32); cs.w += __shfl_xor(cs.w, 32);
    cm.x = fmaxf(cm.x, __shfl_xor(cm.x, 32));
    cm.y = fmaxf(cm.y, __shfl_xor(cm.y, 32));
    cm.z = fmaxf(cm.z, __shfl_xor(cm.z, 32));
    cm.w = fmaxf(cm.w, __shfl_xor(cm.w, 32));

    if (lane < 32) {
        const int w0 = 4 * lane;
        xcat2[128 + w0 + 0] = make_float2(cs.x * (1.f / 128.f), cm.x);
        xcat2[128 + w0 + 1] = make_float2(cs.y * (1.f / 128.f), cm.y);
        xcat2[128 + w0 + 2] = make_float2(cs.z * (1.f / 128.f), cm.z);
        xcat2[128 + w0 + 3] = make_float2(cs.w * (1.f / 128.f), cm.w);
    }

    float gs = (cs.x + cs.y) + (cs.z + cs.w);
    float gm = fmaxf(fmaxf(cm.x, cm.y), fmaxf(cm.z, cm.w));
    #pragma unroll
    for (int m = 16; m >= 1; m >>= 1) {
        gs += __shfl_xor(gs, m);
        gm = fmaxf(gm, __shfl_xor(gm, m));
    }
    if (lane == 0) xcat2[256] = make_float2(gs * (1.f / 16384.f), gm);
}

// ---------------- k2: distributed y -> attention rows -----------------------
__global__ __launch_bounds__(256, 2) void k2_attn(
    const float* __restrict__ xcat,
    const float* __restrict__ w1, const float* __restrict__ b1,
    const float* __restrict__ gam, const float* __restrict__ bet,
    const float* __restrict__ mu, const float* __restrict__ var,
    const float* __restrict__ w2, const float* __restrict__ b2,
    const float* __restrict__ w3, const float* __restrict__ b3,
    float* __restrict__ ahg, float* __restrict__ awg, float* __restrict__ y256g)
{
    const int b = blockIdx.x;
    const int n = b >> 5, cg = b & 31;
    const int tid = threadIdx.x;
    __shared__ __align__(16) float smf[6448];

    float* w1s = smf;
    float* red = smf + 2048;
    float* ys  = smf + 6272;
    const float2* xc2 = reinterpret_cast<const float2*>(xcat) + (size_t)n * C_ * S_;
    const int s0 = cg * 8;

    for (int i = tid; i < TC_ * C_; i += 256) w1s[i] = w1[i];
    __syncthreads();

    {   // stage A
        const int cgrp = tid >> 3, si = tid & 7;
        const int s = s0 + si;
        float acc[16];
        #pragma unroll
        for (int j = 0; j < 16; ++j) acc[j] = 0.f;
        #pragma unroll
        for (int i = 0; i < 8; ++i) {
            const int c = cgrp * 8 + i;
            const float2 v = xc2[c * S_ + s];
            #pragma unroll
            for (int t = 0; t < TC_; ++t) {
                const float w = w1s[t * C_ + c];
                acc[t * 2 + 0] += v.x * w;
                acc[t * 2 + 1] += v.y * w;
            }
        }
        #pragma unroll
        for (int j = 0; j < 16; ++j) red[(si * 16 + j) * 33 + cgrp] = acc[j];
    }
    __syncthreads();

    if (tid < 128) {   // stage B
        const int si2 = tid >> 4, j = tid & 15, t = j >> 1;
        float z = 0.f;
        #pragma unroll
        for (int g = 0; g < 32; ++g) z += red[(si2 * 16 + j) * 33 + g];
        const float inv = gam[t] * rsqrtf(var[t] + EPS_);
        float y = (z + b1[t] - mu[t]) * inv + bet[t];
        y = y * fminf(fmaxf(y + 3.f, 0.f), 6.f) * (1.f / 6.f);
        ys[si2 * 17 + j] = y;
    }
    __syncthreads();

    if (cg == BPN - 1) {   // tail s = 256 -> y256g
        const int c = tid;
        const float2 v = xc2[c * S_ + 256];
        float pj[16];
        #pragma unroll
        for (int t = 0; t < TC_; ++t) {
            const float w = w1s[t * C_ + c];
            pj[t * 2 + 0] = v.x * w;
            pj[t * 2 + 1] = v.y * w;
        }
        __syncthreads();
        float* red2 = smf;
        float* redB = smf + 4400;
        #pragma unroll
        for (int j = 0; j < 16; ++j) red2[tid * 17 + j] = pj[j];
        __syncthreads();
        {
            const int g = tid >> 4, j = tid & 15;
            float z = 0.f;
            #pragma unroll
            for (int m = 0; m < 16; ++m) z += red2[(g * 16 + m) * 17 + j];
            redB[j * 17 + g] = z;
        }
        __syncthreads();
        if (tid < 16) {
            const int j = tid, t = j >> 1;
            float z = 0.f;
            #pragma unroll
            for (int g = 0; g < 16; ++g) z += redB[j * 17 + g];
            const float inv = gam[t] * rsqrtf(var[t] + EPS_);
            float y = (z + b1[t] - mu[t]) * inv + bet[t];
            y = y * fminf(fmaxf(y + 3.f, 0.f), 6.f) * (1.f / 6.f);
            y256g[n * 16 + j] = y;
        }
        __syncthreads();
    }

    {   // stage C
        const int o = tid;
        const bool is_h = (cg < 16);
        const float* wX = is_h ? w2 : w3;
        const float zb = is_h ? b2[o] : b3[o];
        float4 wr[4];
        const float4* wv = reinterpret_cast<const float4*>(wX + o * 16);
        #pragma unroll
        for (int q = 0; q < 4; ++q) wr[q] = wv[q];

        float r[8];
        #pragma unroll
        for (int si = 0; si < 8; ++si) {
            float z = zb;
            #pragma unroll
            for (int q = 0; q < 4; ++q) {
                z += ys[si * 17 + q * 4 + 0] * wr[q].x
                   + ys[si * 17 + q * 4 + 1] * wr[q].y
                   + ys[si * 17 + q * 4 + 2] * wr[q].z
                   + ys[si * 17 + q * 4 + 3] * wr[q].w;
            }
            r[si] = 1.f / (1.f + expf(-z));
        }
        float* og = is_h ? (ahg + (size_t)(n * C_ + o) * H_ + s0)
                         : (awg + (size_t)(n * C_ + o) * W_ + (s0 - 128));
        *reinterpret_cast<float4*>(og)     = make_float4(r[0], r[1], r[2], r[3]);
        *reinterpret_cast<float4*>(og + 4) = make_float4(r[4], r[5], r[6], r[7]);
    }
}

// ---------------- k3: half-plane per wave, 32 waves/CU, nt-stores -----------
__global__ __launch_bounds__(256, 8) void k3_apply(
    const float* __restrict__ x,
    const float* __restrict__ w4, const float* __restrict__ b4,
    const float* __restrict__ ahg, const float* __restrict__ awg,
    const float* __restrict__ y256g, float* __restrict__ out)
{
    const int tid = threadIdx.x, lane = tid & 63, wv = tid >> 6;
    const int gw = blockIdx.x * 4 + wv;             // global wave id (8192)
    const int p = gw >> 1, hh = gw & 1;             // plane, half (rows 64*hh..)
    const int n = p >> 8, o = p & 255;

    // a_c for this plane (redundant per lane, 16 FMA + exp)
    float z = b4[o];
    const float4* w4v = reinterpret_cast<const float4*>(w4 + o * 16);
    const float4* yv  = reinterpret_cast<const float4*>(y256g + n * 16);
    #pragma unroll
    for (int q = 0; q < 4; ++q) {
        const float4 ww = w4v[q], yy = yv[q];
        z += yy.x * ww.x + yy.y * ww.y + yy.z * ww.z + yy.w * ww.w;
    }
    const float ac = 1.f / (1.f + expf(-z));

    // a_w: lane-resident (col block lane&31, fixed across iterations)
    const float4 aw = reinterpret_cast<const float4*>(awg + (size_t)p * W_)[lane & 31];

    const f4n* x4 = reinterpret_cast<const f4n*>(x) + (size_t)p * 4096 + hh * 2048;
    f4n* o4 = reinterpret_cast<f4n*>(out) + (size_t)p * 4096 + hh * 2048;
    const float* ah = ahg + (size_t)p * H_ + hh * 64;
    const int half = lane >> 5;

    #pragma unroll 4
    for (int it = 0; it < 32; ++it) {
        f4n v = x4[it * 64 + lane];
        const float s = ac * ah[2 * it + half];     // L1-broadcast
        v.x *= s * aw.x; v.y *= s * aw.y; v.z *= s * aw.z; v.w *= s * aw.w;
        __builtin_nontemporal_store(v, &o4[it * 64 + lane]);
    }
}

extern "C" void kernel_launch(void* const* d_in, const int* in_sizes, int n_in,
                              void* d_out, int out_size, void* d_ws, size_t ws_size,
                              hipStream_t stream) {
    const float* x   = (const float*)d_in[0];
    const float* w1  = (const float*)d_in[1];
    const float* b1  = (const float*)d_in[2];
    const float* gam = (const float*)d_in[3];
    const float* bet = (const float*)d_in[4];
    const float* mu  = (const float*)d_in[5];
    const float* var = (const float*)d_in[6];
    const float* w2  = (const float*)d_in[7];
    const float* b2  = (const float*)d_in[8];
    const float* w3  = (const float*)d_in[9];
    const float* b3  = (const float*)d_in[10];
    const float* w4  = (const float*)d_in[11];
    const float* b4  = (const float*)d_in[12];

    float* ws    = (float*)d_ws;
    float* xcat  = ws + XCT_OFF;
    float* ahg   = ws + AH_OFF;
    float* awg   = ws + AW_OFF;
    float* y256g = ws + Y256_OFF;
    float* out   = (float*)d_out;

    k1_stats<<<1024, 256, 0, stream>>>(x, xcat);
    k2_attn<<<NBLK, 256, 0, stream>>>(xcat, w1, b1, gam, bet, mu, var,
                                      w2, b2, w3, b3, ahg, awg, y256g);
    k3_apply<<<2048, 256, 0, stream>>>(x, w4, b4, ahg, awg, y256g, out);
}